// Round 7
// baseline (55.002 us; speedup 1.0000x reference)
//
#include <hip/hip_runtime.h>
#include <hip/hip_bf16.h>

#define KDIM  1024
#define NOUT  1024
#define NTOK  8192
#define NCB   16
#define BM    256
#define BN    128
#define BK    64
#define BUFSZ 49152   // A 32KB + B 16KB per K-tile buffer
#define NBUF  3

typedef __attribute__((ext_vector_type(8))) short short8;
typedef __attribute__((ext_vector_type(4))) float f32x4;

__device__ static inline unsigned short f2bf(float f) {
    unsigned int u = __float_as_uint(f);
    return (unsigned short)((u + 0x7FFFu + ((u >> 16) & 1u)) >> 16);
}

__device__ static inline float bf2f(unsigned int h) {
    return __uint_as_float(h << 16);
}

__device__ static inline unsigned int pk_bf16(float a, float b) {
    __hip_bfloat162 h = __float22bfloat162_rn(float2{a, b});
    return *reinterpret_cast<unsigned int*>(&h);
}

__device__ static inline void async_copy16(const void* g, void* l) {
    __builtin_amdgcn_global_load_lds(
        (const __attribute__((address_space(1))) void*)g,
        (__attribute__((address_space(3))) void*)l, 16, 0, 0);
}

// ---- weight fp32 [16][1024][64] -> bf16 Bt [n=1024][k=1024], n = h*64+o ----
__global__ __launch_bounds__(256) void conv_w_kernel(const float* __restrict__ W,
                                                     unsigned short* __restrict__ Bt) {
    int u = blockIdx.x * 256 + threadIdx.x;
    int n  = u & (NOUT - 1);
    int k0 = (u >> 10) << 3;
    int h = n >> 6, o = n & 63;
    const float* src = W + (size_t)h * KDIM * 64 + o;
    short8 v;
#pragma unroll
    for (int j = 0; j < 8; ++j)
        v[j] = (short)f2bf(src[(size_t)(k0 + j) * 64]);
    *(short8*)(Bt + (size_t)n * KDIM + k0) = v;
}

// B-tile stage: 128x64 bf16 via gload_lds, dest linear, XOR chunk-swizzle in
// per-lane global source address (cs = cd ^ (row&7), involution).
__device__ __forceinline__ void stage_b(const unsigned short* __restrict__ Bt,
                                        char* lbase, int tid, int n0, int kel) {
    unsigned short* Bl = (unsigned short*)(lbase + 32768);
#pragma unroll
    for (int i = 0; i < 2; ++i) {
        int s = i * 512 + tid;
        int row = s >> 3;
        int cs = (s & 7) ^ (row & 7);
        async_copy16(Bt + (size_t)(n0 + row) * KDIM + kel + cs * 8, Bl + s * 8);
    }
}

// x-tile loads: 8 coalesced float4 per thread (flat idx = i*512+tid:
// row = idx>>4 (0..255), c = idx&15 (float4 within row)).
__device__ __forceinline__ void load_x(const float* __restrict__ x, int tid,
                                       int m0, int kel, float4 (&rx)[8]) {
#pragma unroll
    for (int i = 0; i < 8; ++i) {
        int idx = i * 512 + tid;
        int row = idx >> 4, c = idx & 15;
        rx[i] = *(const float4*)(x + (size_t)(m0 + row) * KDIM + kel + c * 4);
    }
}

// convert + ds_write A-tile (8 x ds_write_b64), write-side XOR swizzle:
// 16B chunk (c>>1) goes to (c>>1)^(row&7), 8B half = c&1.
__device__ __forceinline__ void write_a(char* lbase, int tid, float4 (&rx)[8]) {
    unsigned short* Al = (unsigned short*)lbase;
#pragma unroll
    for (int i = 0; i < 8; ++i) {
        int idx = i * 512 + tid;
        int row = idx >> 4, c = idx & 15;
        uint2 v;
        v.x = pk_bf16(rx[i].x, rx[i].y);
        v.y = pk_bf16(rx[i].z, rx[i].w);
        *(uint2*)(Al + row * 64 + (((c >> 1) ^ (row & 7)) << 3) + ((c & 1) << 2)) = v;
    }
}

// one pipelined K-step. Issue order per step: 8 x-loads, 2 B-gloads.
// VM=12 in steady state (allows B(kt+1)? no: completes through x(kt+1)).
template <int VM, bool STAGE, bool CONSUME>
__device__ __forceinline__ void gemm_step(const float* __restrict__ x,
                                          const unsigned short* __restrict__ Bt,
                                          char* lds, int tid, int m0, int n0, int kt,
                                          int wm, int wn, int r15, int q,
                                          float4 (&rx_fill)[8], float4 (&rx_cons)[8],
                                          f32x4 (&acc)[4][4]) {
    if (STAGE) {
        load_x(x, tid, m0, (kt + 2) * BK, rx_fill);
        stage_b(Bt, lds + ((kt + 2) % NBUF) * BUFSZ, tid, n0, (kt + 2) * BK);
    }
    asm volatile("s_waitcnt vmcnt(%0)" :: "i"(VM) : "memory");
    __builtin_amdgcn_sched_barrier(0);
    __builtin_amdgcn_s_barrier();
    __builtin_amdgcn_sched_barrier(0);

    const unsigned short* Al = (const unsigned short*)(lds + (kt % NBUF) * BUFSZ);
    const unsigned short* Bl = (const unsigned short*)(lds + (kt % NBUF) * BUFSZ + 32768);
    short8 af[4][2], bf[4][2];
#pragma unroll
    for (int mf = 0; mf < 4; ++mf)
#pragma unroll
        for (int kk = 0; kk < 2; ++kk) {
            int row = wm * 64 + mf * 16 + r15;
            int c = kk * 4 + q;
            af[mf][kk] = *(const short8*)(Al + row * 64 + ((c ^ (row & 7)) << 3));
        }
#pragma unroll
    for (int nf = 0; nf < 4; ++nf)
#pragma unroll
        for (int kk = 0; kk < 2; ++kk) {
            int row = wn * 64 + nf * 16 + r15;
            int c = kk * 4 + q;
            bf[nf][kk] = *(const short8*)(Bl + row * 64 + ((c ^ (row & 7)) << 3));
        }
    if (CONSUME)
        write_a(lds + ((kt + 1) % NBUF) * BUFSZ, tid, rx_cons);

    asm volatile("s_waitcnt lgkmcnt(0)" ::: "memory");
    __builtin_amdgcn_sched_barrier(0);
    __builtin_amdgcn_s_barrier();
    __builtin_amdgcn_sched_barrier(0);

    __builtin_amdgcn_s_setprio(1);
#pragma unroll
    for (int kk = 0; kk < 2; ++kk)
#pragma unroll
        for (int mf = 0; mf < 4; ++mf)
#pragma unroll
            for (int nf = 0; nf < 4; ++nf)
                acc[mf][nf] = __builtin_amdgcn_mfma_f32_16x16x32_bf16(af[mf][kk], bf[nf][kk], acc[mf][nf], 0, 0, 0);
    __builtin_amdgcn_s_setprio(0);
}

// ---- GEMM fused with x->bf16 staging. BM=256 BN=128, 8 waves (4m x 2n),
// 3-buffer counted-vmcnt pipeline, XCD remap. Y[m][n] = sum_k bf16(x)[m][k]*Bt[n][k].
__global__ __launch_bounds__(512, 2) void gemm_kernel(const float* __restrict__ x,
                                                      const unsigned short* __restrict__ Bt,
                                                      unsigned short* __restrict__ Y) {
    extern __shared__ char lds[];   // 3 * 48KB

    const int id  = blockIdx.x;
    const int xcd = id & 7;
    const int j   = id >> 3;
    const int m0  = (xcd * 4 + (j >> 3)) * BM;
    const int n0  = (j & 7) * BN;

    const int tid  = threadIdx.x;
    const int lane = tid & 63;
    const int w    = tid >> 6;
    const int wm   = w >> 1;
    const int wn   = w & 1;
    const int r15  = lane & 15;
    const int q    = lane >> 4;

    f32x4 acc[4][4];
#pragma unroll
    for (int mf = 0; mf < 4; ++mf)
#pragma unroll
        for (int nf = 0; nf < 4; ++nf)
            acc[mf][nf] = (f32x4){0.f, 0.f, 0.f, 0.f};

    float4 rxA[8], rxB[8];

    // ---- prologue: A(0) via regs, B(0)/B(1) via gload_lds, x(1) in flight ----
    load_x(x, tid, m0, 0, rxA);
    stage_b(Bt, lds, tid, n0, 0);
    asm volatile("s_waitcnt vmcnt(2)" ::: "memory");   // x(0) done, B(0) may fly
    __builtin_amdgcn_sched_barrier(0);
    write_a(lds, tid, rxA);
    load_x(x, tid, m0, BK, rxB);
    stage_b(Bt, lds + BUFSZ, tid, n0, BK);
    asm volatile("s_waitcnt lgkmcnt(0)" ::: "memory"); // A(0) writes visible
    __builtin_amdgcn_sched_barrier(0);
    __builtin_amdgcn_s_barrier();

    // steady state: even steps fill rxA / consume rxB, odd steps swap
#pragma unroll 1
    for (int t2 = 0; t2 < 7; ++t2) {
        gemm_step<12, true, true>(x, Bt, lds, tid, m0, n0, 2 * t2,     wm, wn, r15, q, rxA, rxB, acc);
        gemm_step<12, true, true>(x, Bt, lds, tid, m0, n0, 2 * t2 + 1, wm, wn, r15, q, rxB, rxA, acc);
    }
    gemm_step<2, false, true >(x, Bt, lds, tid, m0, n0, 14, wm, wn, r15, q, rxA, rxB, acc);
    gemm_step<0, false, false>(x, Bt, lds, tid, m0, n0, 15, wm, wn, r15, q, rxA, rxA, acc);

    // write back: D layout col=lane&15, row=(lane>>4)*4+r
#pragma unroll
    for (int mf = 0; mf < 4; ++mf)
#pragma unroll
        for (int nf = 0; nf < 4; ++nf) {
            int col = n0 + wn * 64 + nf * 16 + r15;
#pragma unroll
            for (int r = 0; r < 4; ++r) {
                int row = m0 + wm * 64 + mf * 16 + q * 4 + r;
                Y[(size_t)row * NOUT + col] = f2bf(acc[mf][nf][r]);
            }
        }
}

// ---- epilogue: outer product + mean*sqrt(h) + rms_norm; 1 block/token ----
__global__ __launch_bounds__(256) void epilogue_kernel(const unsigned short* __restrict__ Y,
                                                       float* __restrict__ out) {
    __shared__ float ylds[1024];
    __shared__ float red[4];

    const int t = blockIdx.x;
    const int tid = threadIdx.x;
    const unsigned short* yrow = Y + (size_t)t * NOUT;

    {
        uint2 raw = *(const uint2*)(yrow + tid * 4);
        ylds[tid * 4 + 0] = bf2f(raw.x & 0xffffu);
        ylds[tid * 4 + 1] = bf2f(raw.x >> 16);
        ylds[tid * 4 + 2] = bf2f(raw.y & 0xffffu);
        ylds[tid * 4 + 3] = bf2f(raw.y >> 16);
    }
    __syncthreads();

    const int jj = tid >> 3;
    const int k0 = (tid & 7) * 4;

    float o0 = 0.f, o1 = 0.f, o2 = 0.f, o3 = 0.f;
#pragma unroll
    for (int h = 0; h < NCB; ++h) {
        float a = ylds[h * 64 + jj];
        float4 bb = *(const float4*)&ylds[h * 64 + 32 + k0];
        o0 += a * bb.x; o1 += a * bb.y; o2 += a * bb.z; o3 += a * bb.w;
    }
    o0 *= 0.25f; o1 *= 0.25f; o2 *= 0.25f; o3 *= 0.25f;

    float ss = o0 * o0 + o1 * o1 + o2 * o2 + o3 * o3;
#pragma unroll
    for (int off = 32; off >= 1; off >>= 1)
        ss += __shfl_xor(ss, off, 64);

    const int lane = tid & 63, wv = tid >> 6;
    if (lane == 0) red[wv] = ss;
    __syncthreads();
    float tot = red[0] + red[1] + red[2] + red[3];
    float scale = rsqrtf(tot * (1.0f / 1024.0f) + 1e-12f);

    float4 o;
    o.x = o0 * scale; o.y = o1 * scale; o.z = o2 * scale; o.w = o3 * scale;
    *(float4*)(out + (size_t)t * 1024 + tid * 4) = o;
}

extern "C" void kernel_launch(void* const* d_in, const int* in_sizes, int n_in,
                              void* d_out, int out_size, void* d_ws, size_t ws_size,
                              hipStream_t stream) {
    const float* x   = (const float*)d_in[0];
    const float* wgt = (const float*)d_in[1];
    float* out = (float*)d_out;

    unsigned short* Bt = (unsigned short*)d_ws;                       //  2 MB
    unsigned short* Y  = (unsigned short*)((char*)d_ws + (2u << 20)); // 16 MB

    (void)hipFuncSetAttribute((const void*)gemm_kernel,
                              hipFuncAttributeMaxDynamicSharedMemorySize, NBUF * BUFSZ);

    conv_w_kernel<<<NOUT * KDIM / 8 / 256, 256, 0, stream>>>(wgt, Bt);
    gemm_kernel<<<(NTOK / BM) * (NOUT / BN), 512, NBUF * BUFSZ, stream>>>(x, Bt, Y);
    epilogue_kernel<<<NTOK, 256, 0, stream>>>(Y, out);
}

// Round 8
// 50.001 us; speedup vs baseline: 1.1000x; 1.1000x over previous
//
#include <hip/hip_runtime.h>
#include <hip/hip_bf16.h>

#define KDIM  1024
#define NOUT  1024
#define NTOK  8192
#define NCB   16
#define BM    128
#define BN    128
#define BK    32
#define TILEB 16384   // bytes per K-tile buffer: A 8KB + B 8KB
#define NBUF  3

typedef __attribute__((ext_vector_type(8))) short short8;
typedef __attribute__((ext_vector_type(4))) float f32x4;

__device__ static inline unsigned short f2bf(float f) {
    unsigned int u = __float_as_uint(f);
    return (unsigned short)((u + 0x7FFFu + ((u >> 16) & 1u)) >> 16);
}

__device__ static inline float bf2f(unsigned int h) {
    return __uint_as_float(h << 16);
}

__device__ static inline void async_copy16(const void* g, void* l) {
    __builtin_amdgcn_global_load_lds(
        (const __attribute__((address_space(1))) void*)g,
        (__attribute__((address_space(3))) void*)l, 16, 0, 0);
}

// ---- combined convert: blocks [0,4096) do x->A, [4096,4608) do W->Bt ----
__global__ __launch_bounds__(256) void conv_kernel(const float* __restrict__ x,
                                                   const float* __restrict__ W,
                                                   unsigned short* __restrict__ A,
                                                   unsigned short* __restrict__ Bt) {
    int b = blockIdx.x;
    if (b < 4096) {
        int u = b * 256 + threadIdx.x;
        const float* src = x + (size_t)u * 8;
        float4 v0 = *(const float4*)(src);
        float4 v1 = *(const float4*)(src + 4);
        short8 o;
        o[0] = (short)f2bf(v0.x); o[1] = (short)f2bf(v0.y);
        o[2] = (short)f2bf(v0.z); o[3] = (short)f2bf(v0.w);
        o[4] = (short)f2bf(v1.x); o[5] = (short)f2bf(v1.y);
        o[6] = (short)f2bf(v1.z); o[7] = (short)f2bf(v1.w);
        *(short8*)(A + (size_t)u * 8) = o;
    } else {
        int u = (b - 4096) * 256 + threadIdx.x;
        int n  = u & (NOUT - 1);
        int k0 = (u >> 10) << 3;
        int h = n >> 6, o = n & 63;
        const float* src = W + (size_t)h * KDIM * 64 + o;
        short8 v;
#pragma unroll
        for (int j = 0; j < 8; ++j)
            v[j] = (short)f2bf(src[(size_t)(k0 + j) * 64]);
        *(short8*)(Bt + (size_t)n * KDIM + k0) = v;
    }
}

// stage one K-tile: A 128x32 bf16 (8KB) + B 128x32 (8KB), all linear
// (BK=32 -> 64B row stride -> bank-uniform frag reads, no swizzle needed).
__device__ __forceinline__ void stage_tile(const unsigned short* __restrict__ A,
                                           const unsigned short* __restrict__ Bt,
                                           char* lbase, int tid, int m0, int n0, int kel) {
    unsigned short* Al = (unsigned short*)lbase;
    unsigned short* Bl = (unsigned short*)(lbase + 8192);
#pragma unroll
    for (int i = 0; i < 2; ++i) {
        int s = i * 256 + tid;          // 16B slot
        int row = s >> 2, c = s & 3;
        async_copy16(A + (size_t)(m0 + row) * KDIM + kel + c * 8, Al + s * 8);
    }
#pragma unroll
    for (int i = 0; i < 2; ++i) {
        int s = i * 256 + tid;
        int row = s >> 2, c = s & 3;
        async_copy16(Bt + (size_t)(n0 + row) * KDIM + kel + c * 8, Bl + s * 8);
    }
}

// one pipelined K-step: stage(kt+2) -> vmcnt(VM) -> bar -> ds_read frags ->
// lgkmcnt(0) -> bar -> setprio(1) 16 MFMA setprio(0).  4 loads/thread/tile;
// steady-state VM=8 keeps tiles kt+1,kt+2 in flight, never drains to 0.
template <int VM, bool STAGE>
__device__ __forceinline__ void gemm_step(const unsigned short* __restrict__ A,
                                          const unsigned short* __restrict__ Bt,
                                          char* lds, int tid, int m0, int n0, int kt,
                                          int wr, int wc, int r15, int kq,
                                          f32x4 (&acc)[4][4]) {
    if (STAGE)
        stage_tile(A, Bt, lds + ((kt + 2) % NBUF) * TILEB, tid, m0, n0, (kt + 2) * BK);
    asm volatile("s_waitcnt vmcnt(%0)" :: "i"(VM) : "memory");
    __builtin_amdgcn_sched_barrier(0);
    __builtin_amdgcn_s_barrier();

    const unsigned short* Al = (const unsigned short*)(lds + (kt % NBUF) * TILEB);
    const unsigned short* Bl = Al + 4096;
    short8 af[4], bf[4];
#pragma unroll
    for (int mf = 0; mf < 4; ++mf)
        af[mf] = *(const short8*)(Al + (wr + mf * 16 + r15) * 32 + kq);
#pragma unroll
    for (int nf = 0; nf < 4; ++nf)
        bf[nf] = *(const short8*)(Bl + (wc + nf * 16 + r15) * 32 + kq);

    asm volatile("s_waitcnt lgkmcnt(0)" ::: "memory");
    __builtin_amdgcn_sched_barrier(0);
    __builtin_amdgcn_s_barrier();   // buffer (kt)%NBUF now reusable by stage at kt+1

    __builtin_amdgcn_s_setprio(1);
#pragma unroll
    for (int mf = 0; mf < 4; ++mf)
#pragma unroll
        for (int nf = 0; nf < 4; ++nf)
            acc[mf][nf] = __builtin_amdgcn_mfma_f32_16x16x32_bf16(af[mf], bf[nf], acc[mf][nf], 0, 0, 0);
    __builtin_amdgcn_s_setprio(0);
}

// ---- GEMM: Y[m][n] = sum_k A[m][k]*Bt[n][k]; BM=BN=128, 4 waves (2x2),
// 3-buffer counted-vmcnt pipeline, 512 blocks (2-3 co-resident/CU), XCD remap
// (8 n-blocks of an m-panel + 8 m-panels per XCD: 2MB A + 2MB Bt in L2). ----
__global__ __launch_bounds__(256, 3) void gemm_kernel(const unsigned short* __restrict__ A,
                                                      const unsigned short* __restrict__ Bt,
                                                      unsigned short* __restrict__ Y) {
    extern __shared__ char lds[];   // 3 * 16KB

    const int id  = blockIdx.x;
    const int xcd = id & 7;
    const int j   = id >> 3;                  // 0..63
    const int m0  = (xcd * 8 + (j >> 3)) * BM;
    const int n0  = (j & 7) * BN;

    const int tid  = threadIdx.x;
    const int lane = tid & 63;
    const int w    = tid >> 6;
    const int wr   = (w >> 1) * 64;
    const int wc   = (w & 1) * 64;
    const int r15  = lane & 15;
    const int q    = lane >> 4;
    const int kq   = q * 8;

    f32x4 acc[4][4];
#pragma unroll
    for (int mf = 0; mf < 4; ++mf)
#pragma unroll
        for (int nf = 0; nf < 4; ++nf)
            acc[mf][nf] = (f32x4){0.f, 0.f, 0.f, 0.f};

    // prologue: tiles 0 and 1 in flight
    stage_tile(A, Bt, lds,         tid, m0, n0, 0);
    stage_tile(A, Bt, lds + TILEB, tid, m0, n0, BK);

#pragma unroll 2
    for (int kt = 0; kt < 30; ++kt)
        gemm_step<8, true>(A, Bt, lds, tid, m0, n0, kt, wr, wc, r15, kq, acc);
    gemm_step<4, false>(A, Bt, lds, tid, m0, n0, 30, wr, wc, r15, kq, acc);
    gemm_step<0, false>(A, Bt, lds, tid, m0, n0, 31, wr, wc, r15, kq, acc);

    // write back: D layout col=lane&15, row=(lane>>4)*4+r
#pragma unroll
    for (int mf = 0; mf < 4; ++mf)
#pragma unroll
        for (int nf = 0; nf < 4; ++nf) {
            int col = n0 + wc + nf * 16 + r15;
#pragma unroll
            for (int r = 0; r < 4; ++r) {
                int row = m0 + wr + mf * 16 + q * 4 + r;
                Y[(size_t)row * NOUT + col] = f2bf(acc[mf][nf][r]);
            }
        }
}

// ---- epilogue: outer product + mean*sqrt(h) + rms_norm; 1 block/token ----
__global__ __launch_bounds__(256) void epilogue_kernel(const unsigned short* __restrict__ Y,
                                                       float* __restrict__ out) {
    __shared__ float ylds[1024];
    __shared__ float red[4];

    const int t = blockIdx.x;
    const int tid = threadIdx.x;
    const unsigned short* yrow = Y + (size_t)t * NOUT;

    {
        uint2 raw = *(const uint2*)(yrow + tid * 4);
        ylds[tid * 4 + 0] = bf2f(raw.x & 0xffffu);
        ylds[tid * 4 + 1] = bf2f(raw.x >> 16);
        ylds[tid * 4 + 2] = bf2f(raw.y & 0xffffu);
        ylds[tid * 4 + 3] = bf2f(raw.y >> 16);
    }
    __syncthreads();

    const int jj = tid >> 3;
    const int k0 = (tid & 7) * 4;

    float o0 = 0.f, o1 = 0.f, o2 = 0.f, o3 = 0.f;
#pragma unroll
    for (int h = 0; h < NCB; ++h) {
        float a = ylds[h * 64 + jj];
        float4 bb = *(const float4*)&ylds[h * 64 + 32 + k0];
        o0 += a * bb.x; o1 += a * bb.y; o2 += a * bb.z; o3 += a * bb.w;
    }
    o0 *= 0.25f; o1 *= 0.25f; o2 *= 0.25f; o3 *= 0.25f;

    float ss = o0 * o0 + o1 * o1 + o2 * o2 + o3 * o3;
#pragma unroll
    for (int off = 32; off >= 1; off >>= 1)
        ss += __shfl_xor(ss, off, 64);

    const int lane = tid & 63, wv = tid >> 6;
    if (lane == 0) red[wv] = ss;
    __syncthreads();
    float tot = red[0] + red[1] + red[2] + red[3];
    float scale = rsqrtf(tot * (1.0f / 1024.0f) + 1e-12f);

    float4 o;
    o.x = o0 * scale; o.y = o1 * scale; o.z = o2 * scale; o.w = o3 * scale;
    *(float4*)(out + (size_t)t * 1024 + tid * 4) = o;
}

extern "C" void kernel_launch(void* const* d_in, const int* in_sizes, int n_in,
                              void* d_out, int out_size, void* d_ws, size_t ws_size,
                              hipStream_t stream) {
    const float* x   = (const float*)d_in[0];
    const float* wgt = (const float*)d_in[1];
    float* out = (float*)d_out;

    unsigned short* A  = (unsigned short*)d_ws;                        // 16 MB
    unsigned short* Bt = (unsigned short*)((char*)d_ws + (16u << 20)); //  2 MB
    unsigned short* Y  = (unsigned short*)((char*)d_ws + (18u << 20)); // 16 MB

    (void)hipFuncSetAttribute((const void*)gemm_kernel,
                              hipFuncAttributeMaxDynamicSharedMemorySize, NBUF * TILEB);

    conv_kernel<<<4096 + 512, 256, 0, stream>>>(x, wgt, A, Bt);
    gemm_kernel<<<(NTOK / BM) * (NOUT / BN), 256, NBUF * TILEB, stream>>>(A, Bt, Y);
    epilogue_kernel<<<NTOK, 256, 0, stream>>>(Y, out);
}